// Round 5
// baseline (152.879 us; speedup 1.0000x reference)
//
#include <hip/hip_runtime.h>

// PointPillars voxelization, MI355X — round 4 (resubmit; prior run died to
// container infra failure, not a kernel error).
// Grid: 400 x 400 x 1 = 160000 cells. MAX_VOX=60000, MAX_PTS=32, feats=5.
// d_out (float32): voxels [60000,32,5], coords zyx [60000,3], num_points [60000]
//
// Structure: ~62% of in-range points fall in cells whose voxel id >= MAX_VOX
// (voxel ids assigned in ascending flat-cell order; ~159k occupied cells for
// 60k voxel slots). So:
//   1. k_count: count per cell + memoize each point's cell id (coalesced int4).
//   2. scanA/scanB: occupancy scan -> per-cell voxel id (-1 if dead), inverse map.
//   3. k_scatter2: only points with live voxel id (~300k of 1.2M) do the
//      scattered slot write, into a 7.7MB (MAXV*32) array instead of 20.5MB.
//   4. k_finalize: wave/voxel, rank-sort <=32 keys, gather rows, float4 writes.

constexpr int GXc = 400;
constexpr int GYc = 400;
constexpr int NCELL = GXc * GYc;       // 160000
constexpr int MAXV  = 60000;
constexpr int MAXP  = 32;
constexpr int NF    = 5;

constexpr int SCAN_B = 256;
constexpr int SCAN_E = 8;
constexpr int SCAN_TILE = SCAN_B * SCAN_E;                    // 2048
constexpr int NSCANBLK = (NCELL + SCAN_TILE - 1) / SCAN_TILE; // 79

__device__ __forceinline__ int point_cell(float x, float y, float z) {
    // floor((p - vmin)/vsize), vsize=(0.25,0.25,8), vmin=(-50,-50,-5) — exact
    int cx = (int)floorf((x + 50.0f) * 4.0f);
    int cy = (int)floorf((y + 50.0f) * 4.0f);
    int cz = (int)floorf((z + 5.0f) * 0.125f);
    if (cx < 0 || cx >= GXc || cy < 0 || cy >= GYc || cz != 0) return -1;
    return cy * GXc + cx;
}

// Pass 1: per-cell counts (atomics only) + memoized per-point cell id.
__global__ void __launch_bounds__(256)
k_count(const float* __restrict__ pts, int N,
        int* __restrict__ cursor, int* __restrict__ cellId) {
    int t = blockIdx.x * blockDim.x + threadIdx.x;
    int i0 = t * 4;
    if (i0 >= N) return;
    if (N - i0 >= 4) {
        const float4* src = (const float4*)(pts + (size_t)i0 * NF);
        float4 q0 = src[0], q1 = src[1], q2 = src[2], q3 = src[3], q4 = src[4];
        float f[20];
        *(float4*)(f + 0)  = q0; *(float4*)(f + 4)  = q1; *(float4*)(f + 8)  = q2;
        *(float4*)(f + 12) = q3; *(float4*)(f + 16) = q4;
        int cs[4];
        #pragma unroll
        for (int k = 0; k < 4; k++)
            cs[k] = point_cell(f[k * 5 + 0], f[k * 5 + 1], f[k * 5 + 2]);
        *(int4*)(cellId + i0) = make_int4(cs[0], cs[1], cs[2], cs[3]);
        #pragma unroll
        for (int k = 0; k < 4; k++)
            if (cs[k] >= 0) atomicAdd(&cursor[cs[k]], 1);
    } else {
        for (int k = 0; k < N - i0; k++) {
            const float* p = pts + (size_t)(i0 + k) * NF;
            int c = point_cell(p[0], p[1], p[2]);
            cellId[i0 + k] = c;
            if (c >= 0) atomicAdd(&cursor[c], 1);
        }
    }
}

// Per-2048-cell-tile local exclusive scan of occupancy flags.
__global__ void k_scanA(const int* __restrict__ cursor,
                        int* __restrict__ excl, int* __restrict__ blockSums) {
    __shared__ int sh[SCAN_B];
    int base = blockIdx.x * SCAN_TILE;
    int vals[SCAN_E];
    int sum = 0;
    for (int e = 0; e < SCAN_E; e++) {
        int idx = base + threadIdx.x * SCAN_E + e;
        int v = (idx < NCELL && cursor[idx] > 0) ? 1 : 0;
        vals[e] = sum;
        sum += v;
    }
    sh[threadIdx.x] = sum;
    __syncthreads();
    for (int off = 1; off < SCAN_B; off <<= 1) {
        int t = (threadIdx.x >= (unsigned)off) ? sh[threadIdx.x - off] : 0;
        __syncthreads();
        sh[threadIdx.x] += t;
        __syncthreads();
    }
    int thrExcl = (threadIdx.x == 0) ? 0 : sh[threadIdx.x - 1];
    for (int e = 0; e < SCAN_E; e++) {
        int idx = base + threadIdx.x * SCAN_E + e;
        if (idx < NCELL) excl[idx] = thrExcl + vals[e];
    }
    if (threadIdx.x == SCAN_B - 1) blockSums[blockIdx.x] = sh[SCAN_B - 1];
}

// Re-scan the 79 block sums in LDS per block; emit per-cell voxel id
// (-1 for empty or >= MAXV) and the voxel->cell inverse map.
__global__ void k_scanB(const int* __restrict__ cursor,
                        const int* __restrict__ excl,
                        const int* __restrict__ blockSums,
                        int* __restrict__ voxId,
                        int* __restrict__ cellOfVox,
                        int* __restrict__ nvoxOut) {
    __shared__ int sb[128];
    int tid = threadIdx.x;
    if (tid < 128) sb[tid] = (tid < NSCANBLK) ? blockSums[tid] : 0;
    __syncthreads();
    for (int off = 1; off < 128; off <<= 1) {
        int t = (tid < 128 && tid >= off) ? sb[tid - off] : 0;
        __syncthreads();
        if (tid < 128) sb[tid] += t;
        __syncthreads();
    }
    int c = blockIdx.x * blockDim.x + tid;
    if (c < NCELL) {
        int vi = -1;
        if (cursor[c] > 0) {
            int blk = c / SCAN_TILE;
            int basev = (blk == 0) ? 0 : sb[blk - 1];
            int v = basev + excl[c];
            if (v < MAXV) { vi = v; cellOfVox[v] = c; }
        }
        voxId[c] = vi;
    }
    if (blockIdx.x == 0 && tid == 0) {
        int tot = sb[NSCANBLK - 1];
        *nvoxOut = tot < MAXV ? tot : MAXV;
    }
}

// Pass 2: scatter only live points' indices into voxel-indexed slots.
__global__ void __launch_bounds__(256)
k_scatter2(const int* __restrict__ cellId, int N,
           const int* __restrict__ voxId,
           int* __restrict__ cursor2, int* __restrict__ slots) {
    int t = blockIdx.x * blockDim.x + threadIdx.x;
    int i0 = t * 4;
    if (i0 >= N) return;
    if (N - i0 >= 4) {
        int4 cc = *(const int4*)(cellId + i0);
        int cs[4] = {cc.x, cc.y, cc.z, cc.w};
        #pragma unroll
        for (int k = 0; k < 4; k++) {
            int c = cs[k];
            if (c >= 0) {
                int v = voxId[c];
                if (v >= 0) {
                    int pos = atomicAdd(&cursor2[c], 1);
                    if (pos < MAXP) slots[v * MAXP + pos] = i0 + k;
                }
            }
        }
    } else {
        for (int k = 0; k < N - i0; k++) {
            int c = cellId[i0 + k];
            if (c >= 0) {
                int v = voxId[c];
                if (v >= 0) {
                    int pos = atomicAdd(&cursor2[c], 1);
                    if (pos < MAXP) slots[v * MAXP + pos] = i0 + k;
                }
            }
        }
    }
}

// One wave per voxel: parallel rank-sort of <=32 original indices, gather
// rows into LDS, write coalesced float4s. Dead voxels write zeros.
__global__ void __launch_bounds__(256)
k_finalize(const float* __restrict__ pts,
           const int* __restrict__ cursor,
           const int* __restrict__ slots,
           const int* __restrict__ cellOfVox,
           const int* __restrict__ nvoxPtr,
           float* __restrict__ outVox,
           float* __restrict__ outCoord,
           float* __restrict__ outNum) {
    constexpr int WV = 4;                    // waves per block
    __shared__ float s_dat[WV][MAXP * NF];   // 160 floats per voxel
    __shared__ int   s_key[WV][MAXP];
    __shared__ int   s_srt[WV][MAXP];

    int wv   = threadIdx.x >> 6;
    int lane = threadIdx.x & 63;
    int v    = blockIdx.x * WV + wv;         // grid sized so v < MAXV always
    int nvox = *nvoxPtr;

    int c = 0, num = 0, cnt = 0;
    bool live = (v < nvox);
    if (live) {
        c = cellOfVox[v];
        cnt = cursor[c];
        num = cnt < MAXP ? cnt : MAXP;
    }

    if (lane < MAXP)
        s_key[wv][lane] = (live && lane < num) ? slots[v * MAXP + lane] : 0x7fffffff;
    #pragma unroll
    for (int k = 0; k < 3; k++) {
        int idx = lane + 64 * k;
        if (idx < MAXP * NF) s_dat[wv][idx] = 0.0f;
    }
    __syncthreads();

    if (lane < MAXP) {
        int key = s_key[wv][lane];
        int rank = 0;
        #pragma unroll
        for (int j = 0; j < MAXP; j++) rank += (s_key[wv][j] < key) ? 1 : 0;
        if (live && lane < num) s_srt[wv][rank] = key;
    }
    __syncthreads();

    if (live && lane < num) {
        int p = s_srt[wv][lane];
        const float* src = pts + (size_t)p * NF;
        #pragma unroll
        for (int f = 0; f < NF; f++) s_dat[wv][lane * NF + f] = src[f];
    }
    __syncthreads();

    const float4* sv = (const float4*)s_dat[wv];
    float4* dst = (float4*)(outVox + (size_t)v * (MAXP * NF));
    if (lane < 40) dst[lane] = sv[lane];
    if (lane == 40) outCoord[(size_t)v * 3 + 0] = 0.0f;
    if (lane == 41) outCoord[(size_t)v * 3 + 1] = live ? (float)(c / GXc) : 0.0f;
    if (lane == 42) outCoord[(size_t)v * 3 + 2] = live ? (float)(c % GXc) : 0.0f;
    if (lane == 43) outNum[v] = live ? (float)num : 0.0f;
}

extern "C" void kernel_launch(void* const* d_in, const int* in_sizes, int n_in,
                              void* d_out, int out_size, void* d_ws, size_t ws_size,
                              hipStream_t stream) {
    const float* pts = (const float*)d_in[0];
    int N = in_sizes[0] / NF;

    float* out      = (float*)d_out;
    float* outVox   = out;
    float* outCoord = out + (size_t)MAXV * MAXP * NF;
    float* outNum   = outCoord + (size_t)MAXV * 3;

    char* ws = (char*)d_ws;
    auto take = [&](size_t bytes) {
        char* p = ws;
        ws += (bytes + 255) & ~(size_t)255;
        return p;
    };
    int* cursor    = (int*)take((size_t)NCELL * 4);          // pass-1 counts
    int* cursor2   = (int*)take((size_t)NCELL * 4);          // pass-2 arrival (contiguous w/ cursor)
    int* cellId    = (int*)take((size_t)((N + 3) & ~3) * 4);
    int* excl      = (int*)take((size_t)NCELL * 4);
    int* blockSums = (int*)take((size_t)128 * 4);
    int* voxId     = (int*)take((size_t)NCELL * 4);
    int* cellOfVox = (int*)take((size_t)MAXV * 4);
    int* slots     = (int*)take((size_t)MAXV * MAXP * 4);    // 7.68 MB
    int* nvoxBuf   = (int*)take(256);

    // cursor and cursor2 are contiguous (NCELL*4 is 256B-aligned): one memset.
    hipMemsetAsync(cursor, 0, (size_t)NCELL * 8, stream);

    int nt = (N + 3) / 4;
    int nb = (nt + 255) / 256;
    k_count<<<nb, 256, 0, stream>>>(pts, N, cursor, cellId);
    k_scanA<<<NSCANBLK, SCAN_B, 0, stream>>>(cursor, excl, blockSums);
    k_scanB<<<(NCELL + 255) / 256, 256, 0, stream>>>(cursor, excl, blockSums,
                                                     voxId, cellOfVox, nvoxBuf);
    k_scatter2<<<nb, 256, 0, stream>>>(cellId, N, voxId, cursor2, slots);
    k_finalize<<<MAXV / 4, 256, 0, stream>>>(pts, cursor, slots, cellOfVox, nvoxBuf,
                                             outVox, outCoord, outNum);
}

// Round 6
// 129.147 us; speedup vs baseline: 1.1838x; 1.1838x over previous
//
#include <hip/hip_runtime.h>

// PointPillars voxelization, MI355X — round 6.
// Grid: 400 x 400 x 1 = 160000 cells. MAX_VOX=60000, MAX_PTS=32, feats=5.
// d_out (float32): voxels [60000,32,5], coords zyx [60000,3], num_points [60000]
//
// Round-6 theory: the point-pass wall was 793k device atomicAdds (640KB cursor).
//   1. k_bin: NO atomics — write cellId[i] (coalesced int4) + occupied[c]=1 (byte).
//   2. k_scanA/B: scan occupancy bytes -> voxId[c] (-1 if dead/over-cap),
//      cellOfVox inverse map, nvox.
//   3. k_scatter2: only live points (~300k) atomicAdd a voxel-indexed vcount
//      (240KB) and write slot index.
//   4. k_finalize: wave/voxel, rank-sort, 2xfloat4-window gather (2.5x fewer
//      divergent L1 transactions than 5 scalar loads), coalesced float4 out.

constexpr int GXc = 400;
constexpr int GYc = 400;
constexpr int NCELL = GXc * GYc;       // 160000
constexpr int MAXV  = 60000;
constexpr int MAXP  = 32;
constexpr int NF    = 5;

constexpr int SCAN_B = 256;
constexpr int SCAN_E = 8;
constexpr int SCAN_TILE = SCAN_B * SCAN_E;                    // 2048
constexpr int NSCANBLK = (NCELL + SCAN_TILE - 1) / SCAN_TILE; // 79

__device__ __forceinline__ int point_cell(float x, float y, float z) {
    // floor((p - vmin)/vsize), vsize=(0.25,0.25,8), vmin=(-50,-50,-5) — exact
    int cx = (int)floorf((x + 50.0f) * 4.0f);
    int cy = (int)floorf((y + 50.0f) * 4.0f);
    int cz = (int)floorf((z + 5.0f) * 0.125f);
    if (cx < 0 || cx >= GXc || cy < 0 || cy >= GYc || cz != 0) return -1;
    return cy * GXc + cx;
}

// Pass 1: per-point cell id (coalesced) + occupancy byte flags. NO atomics.
__global__ void __launch_bounds__(256)
k_bin(const float* __restrict__ pts, int N,
      unsigned char* __restrict__ occupied, int* __restrict__ cellId) {
    int t = blockIdx.x * blockDim.x + threadIdx.x;
    int i0 = t * 4;
    if (i0 >= N) return;
    if (N - i0 >= 4) {
        const float4* src = (const float4*)(pts + (size_t)i0 * NF);
        float4 q0 = src[0], q1 = src[1], q2 = src[2], q3 = src[3], q4 = src[4];
        float f[20];
        *(float4*)(f + 0)  = q0; *(float4*)(f + 4)  = q1; *(float4*)(f + 8)  = q2;
        *(float4*)(f + 12) = q3; *(float4*)(f + 16) = q4;
        int cs[4];
        #pragma unroll
        for (int k = 0; k < 4; k++)
            cs[k] = point_cell(f[k * 5 + 0], f[k * 5 + 1], f[k * 5 + 2]);
        *(int4*)(cellId + i0) = make_int4(cs[0], cs[1], cs[2], cs[3]);
        #pragma unroll
        for (int k = 0; k < 4; k++)
            if (cs[k] >= 0) occupied[cs[k]] = 1;   // benign race, same value
    } else {
        for (int k = 0; k < N - i0; k++) {
            const float* p = pts + (size_t)(i0 + k) * NF;
            int c = point_cell(p[0], p[1], p[2]);
            cellId[i0 + k] = c;
            if (c >= 0) occupied[c] = 1;
        }
    }
}

// Per-2048-cell-tile local exclusive scan of occupancy flags (byte input).
__global__ void k_scanA(const unsigned char* __restrict__ occupied,
                        int* __restrict__ excl, int* __restrict__ blockSums) {
    __shared__ int sh[SCAN_B];
    int base = blockIdx.x * SCAN_TILE;
    int idx0 = base + threadIdx.x * SCAN_E;           // 8-byte aligned
    unsigned long long occ8 = 0;
    if (idx0 < NCELL) occ8 = *(const unsigned long long*)(occupied + idx0);
    int vals[SCAN_E];
    int sum = 0;
    #pragma unroll
    for (int e = 0; e < SCAN_E; e++) {
        int v = (int)((occ8 >> (8 * e)) & 1ull);
        vals[e] = sum;
        sum += v;
    }
    sh[threadIdx.x] = sum;
    __syncthreads();
    for (int off = 1; off < SCAN_B; off <<= 1) {
        int t = (threadIdx.x >= (unsigned)off) ? sh[threadIdx.x - off] : 0;
        __syncthreads();
        sh[threadIdx.x] += t;
        __syncthreads();
    }
    int thrExcl = (threadIdx.x == 0) ? 0 : sh[threadIdx.x - 1];
    #pragma unroll
    for (int e = 0; e < SCAN_E; e++) {
        int idx = idx0 + e;
        if (idx < NCELL) excl[idx] = thrExcl + vals[e];
    }
    if (threadIdx.x == SCAN_B - 1) blockSums[blockIdx.x] = sh[SCAN_B - 1];
}

// Re-scan the 79 block sums in LDS per block; emit per-cell voxel id
// (-1 for empty or >= MAXV), the voxel->cell inverse map, and nvox.
__global__ void k_scanB(const unsigned char* __restrict__ occupied,
                        const int* __restrict__ excl,
                        const int* __restrict__ blockSums,
                        int* __restrict__ voxId,
                        int* __restrict__ cellOfVox,
                        int* __restrict__ nvoxOut) {
    __shared__ int sb[128];
    int tid = threadIdx.x;
    if (tid < 128) sb[tid] = (tid < NSCANBLK) ? blockSums[tid] : 0;
    __syncthreads();
    for (int off = 1; off < 128; off <<= 1) {
        int t = (tid < 128 && tid >= off) ? sb[tid - off] : 0;
        __syncthreads();
        if (tid < 128) sb[tid] += t;
        __syncthreads();
    }
    int c = blockIdx.x * blockDim.x + tid;
    if (c < NCELL) {
        int vi = -1;
        if (occupied[c]) {
            int blk = c / SCAN_TILE;
            int basev = (blk == 0) ? 0 : sb[blk - 1];
            int v = basev + excl[c];
            if (v < MAXV) { vi = v; cellOfVox[v] = c; }
        }
        voxId[c] = vi;
    }
    if (blockIdx.x == 0 && tid == 0) {
        int tot = sb[NSCANBLK - 1];
        *nvoxOut = tot < MAXV ? tot : MAXV;
    }
}

// Pass 2: live points only — voxel-indexed count + slot write (~300k atomics
// into a 240KB array instead of 793k into 640KB).
__global__ void __launch_bounds__(256)
k_scatter2(const int* __restrict__ cellId, int N,
           const int* __restrict__ voxId,
           int* __restrict__ vcount, int* __restrict__ slots) {
    int t = blockIdx.x * blockDim.x + threadIdx.x;
    int i0 = t * 4;
    if (i0 >= N) return;
    if (N - i0 >= 4) {
        int4 cc = *(const int4*)(cellId + i0);
        int cs[4] = {cc.x, cc.y, cc.z, cc.w};
        #pragma unroll
        for (int k = 0; k < 4; k++) {
            int c = cs[k];
            if (c >= 0) {
                int v = voxId[c];
                if (v >= 0) {
                    int pos = atomicAdd(&vcount[v], 1);
                    if (pos < MAXP) slots[v * MAXP + pos] = i0 + k;
                }
            }
        }
    } else {
        for (int k = 0; k < N - i0; k++) {
            int c = cellId[i0 + k];
            if (c >= 0) {
                int v = voxId[c];
                if (v >= 0) {
                    int pos = atomicAdd(&vcount[v], 1);
                    if (pos < MAXP) slots[v * MAXP + pos] = i0 + k;
                }
            }
        }
    }
}

// One wave per voxel: rank-sort <=32 original indices, gather rows via two
// aligned float4 loads + select, write coalesced float4s. Dead voxels -> zeros.
__global__ void __launch_bounds__(256)
k_finalize(const float* __restrict__ pts, int N,
           const int* __restrict__ vcount,
           const int* __restrict__ slots,
           const int* __restrict__ cellOfVox,
           const int* __restrict__ nvoxPtr,
           float* __restrict__ outVox,
           float* __restrict__ outCoord,
           float* __restrict__ outNum) {
    constexpr int WV = 4;                    // waves per block
    __shared__ float s_dat[WV][MAXP * NF];   // 160 floats per voxel
    __shared__ int   s_key[WV][MAXP];
    __shared__ int   s_srt[WV][MAXP];

    int wv   = threadIdx.x >> 6;
    int lane = threadIdx.x & 63;
    int v    = blockIdx.x * WV + wv;         // grid sized so v < MAXV always
    int nvox = *nvoxPtr;

    int c = 0, num = 0;
    bool live = (v < nvox);
    if (live) {
        c = cellOfVox[v];
        int cnt = vcount[v];
        num = cnt < MAXP ? cnt : MAXP;
    }

    if (lane < MAXP)
        s_key[wv][lane] = (live && lane < num) ? slots[v * MAXP + lane] : 0x7fffffff;
    #pragma unroll
    for (int k = 0; k < 3; k++) {
        int idx = lane + 64 * k;
        if (idx < MAXP * NF) s_dat[wv][idx] = 0.0f;
    }
    __syncthreads();

    if (lane < MAXP) {
        int key = s_key[wv][lane];
        int rank = 0;
        #pragma unroll
        for (int j = 0; j < MAXP; j++) rank += (s_key[wv][j] < key) ? 1 : 0;
        if (live && lane < num) s_srt[wv][rank] = key;
    }
    __syncthreads();

    if (live && lane < num) {
        int p = s_srt[wv][lane];
        size_t byte0 = (size_t)p * 20;
        float r0, r1, r2, r3, r4, r5, r6, r7;
        int sel;
        if (byte0 + 32 <= (size_t)N * 20) {
            const float4* f4 = (const float4*)pts;
            size_t w = byte0 >> 4;
            sel = (int)((byte0 & 15) >> 2);      // 0..3
            float4 qa = f4[w], qb = f4[w + 1];
            r0 = qa.x; r1 = qa.y; r2 = qa.z; r3 = qa.w;
            r4 = qb.x; r5 = qb.y; r6 = qb.z; r7 = qb.w;
        } else {                                  // last row: avoid OOB tail read
            const float* s = pts + (size_t)p * NF;
            r0 = s[0]; r1 = s[1]; r2 = s[2]; r3 = s[3]; r4 = s[4];
            r5 = r6 = r7 = 0.0f; sel = 0;
        }
        float o0 = sel == 0 ? r0 : sel == 1 ? r1 : sel == 2 ? r2 : r3;
        float o1 = sel == 0 ? r1 : sel == 1 ? r2 : sel == 2 ? r3 : r4;
        float o2 = sel == 0 ? r2 : sel == 1 ? r3 : sel == 2 ? r4 : r5;
        float o3 = sel == 0 ? r3 : sel == 1 ? r4 : sel == 2 ? r5 : r6;
        float o4 = sel == 0 ? r4 : sel == 1 ? r5 : sel == 2 ? r6 : r7;
        float* d = &s_dat[wv][lane * NF];
        d[0] = o0; d[1] = o1; d[2] = o2; d[3] = o3; d[4] = o4;
    }
    __syncthreads();

    const float4* sv = (const float4*)s_dat[wv];
    float4* dst = (float4*)(outVox + (size_t)v * (MAXP * NF));
    if (lane < 40) dst[lane] = sv[lane];
    if (lane == 40) outCoord[(size_t)v * 3 + 0] = 0.0f;
    if (lane == 41) outCoord[(size_t)v * 3 + 1] = live ? (float)(c / GXc) : 0.0f;
    if (lane == 42) outCoord[(size_t)v * 3 + 2] = live ? (float)(c % GXc) : 0.0f;
    if (lane == 43) outNum[v] = live ? (float)num : 0.0f;
}

extern "C" void kernel_launch(void* const* d_in, const int* in_sizes, int n_in,
                              void* d_out, int out_size, void* d_ws, size_t ws_size,
                              hipStream_t stream) {
    const float* pts = (const float*)d_in[0];
    int N = in_sizes[0] / NF;

    float* out      = (float*)d_out;
    float* outVox   = out;
    float* outCoord = out + (size_t)MAXV * MAXP * NF;
    float* outNum   = outCoord + (size_t)MAXV * 3;

    char* ws = (char*)d_ws;
    auto take = [&](size_t bytes) {
        char* p = ws;
        ws += (bytes + 255) & ~(size_t)255;
        return p;
    };
    // occupied + vcount contiguous -> single memset of 160KB + 240KB.
    unsigned char* occupied = (unsigned char*)take((size_t)NCELL);
    int* vcount    = (int*)take((size_t)MAXV * 4);
    int* cellId    = (int*)take((size_t)((N + 3) & ~3) * 4);
    int* excl      = (int*)take((size_t)NCELL * 4);
    int* blockSums = (int*)take((size_t)128 * 4);
    int* voxId     = (int*)take((size_t)NCELL * 4);
    int* cellOfVox = (int*)take((size_t)MAXV * 4);
    int* slots     = (int*)take((size_t)MAXV * MAXP * 4);    // 7.68 MB
    int* nvoxBuf   = (int*)take(256);

    size_t zeroBytes = (size_t)((char*)(vcount + MAXV) - (char*)occupied);
    hipMemsetAsync(occupied, 0, zeroBytes, stream);

    int nt = (N + 3) / 4;
    int nb = (nt + 255) / 256;
    k_bin<<<nb, 256, 0, stream>>>(pts, N, occupied, cellId);
    k_scanA<<<NSCANBLK, SCAN_B, 0, stream>>>(occupied, excl, blockSums);
    k_scanB<<<(NCELL + 255) / 256, 256, 0, stream>>>(occupied, excl, blockSums,
                                                     voxId, cellOfVox, nvoxBuf);
    k_scatter2<<<nb, 256, 0, stream>>>(cellId, N, voxId, vcount, slots);
    k_finalize<<<MAXV / 4, 256, 0, stream>>>(pts, N, vcount, slots, cellOfVox,
                                             nvoxBuf, outVox, outCoord, outNum);
}